// Round 1
// baseline (344.108 us; speedup 1.0000x reference)
//
#include <hip/hip_runtime.h>

#define NVERT 40000

// LDS float layout:
//   sW[4544]: WQ[8][8][9] @0 | WK[8][8][8] @576 | WV[6][8][8][9] @1088
//   sF[4][2176]: per-wave, 32 rows x 68 floats (ptm staged, then f overwrites)
//   sAtt[4][32*8]: per-wave per-neighbor coefs [a, a*u0, a*u1, a*u0^2, 2a*u0u1, a*u1^2, -, -]
//   sQ[4][8]
__global__ __launch_bounds__(256, 2)
void ge_attn(const float* __restrict__ x,
             const int* __restrict__ nbr,
             const void* __restrict__ maskp,
             const float* __restrict__ ptm,
             const float* __restrict__ rpu,
             const float* __restrict__ rbasis,
             const float* __restrict__ qcoef,
             const float* __restrict__ kcoef,
             const float* __restrict__ vb0,
             const float* __restrict__ vb1,
             const float* __restrict__ vb2,
             const float* __restrict__ vp0,
             const float* __restrict__ vp1,
             const float* __restrict__ vp2,
             float* __restrict__ out)
{
  __shared__ float sW[4544];
  __shared__ float sF[4][2176];
  __shared__ float sAtt[4][256];
  __shared__ float sQ[4][8];
  __shared__ int sFlagB, sFlagF;

  const int tid  = threadIdx.x;
  const int wv   = tid >> 6;
  const int lane = tid & 63;

  if (tid == 0) { sFlagB = 0; sFlagF = 0; }
  __syncthreads();

  // ---- mask dtype probe (bool bytes vs int32 vs float32), deterministic ----
  {
    const unsigned int* mw = (const unsigned int*)maskp;
    int b0 = 0, b1 = 0;
#pragma unroll
    for (int t = 0; t < 8; ++t) {
      const unsigned int w = mw[tid + (t << 8)];
      b1 |= (w == 0x3F800000u) ? 1 : 0;
      b0 |= (w > 1u && w != 0x3F800000u) ? 1 : 0;
    }
    if (b0) sFlagB = 1;   // packed bool bytes (words with nonzero upper bytes)
    if (b1) sFlagF = 1;   // float 1.0f pattern
  }

  // ---- per-block W precompute into LDS ----
  for (int r = tid; r < 512; r += 256) {
    const int m = r >> 6;
    const int c = (r >> 3) & 7;
    const int i = r & 7;
    const float* par; const float* bas; int ospan, oo;
    switch (m) {
      case 0:  par = qcoef; bas = rbasis; ospan = 1; oo = 0; break;
      case 1:  par = kcoef; bas = rbasis; ospan = 1; oo = 0; break;
      case 2:  par = vp0;   bas = vb0;    ospan = 1; oo = 0; break;
      case 3:  par = vp1;   bas = vb1;    ospan = 2; oo = 0; break;
      case 4:  par = vp1;   bas = vb1;    ospan = 2; oo = 1; break;
      case 5:  par = vp2;   bas = vb2;    ospan = 3; oo = 0; break;
      case 6:  par = vp2;   bas = vb2;    ospan = 3; oo = 1; break;
      default: par = vp2;   bas = vb2;    ospan = 3; oo = 2; break;
    }
    float acc[8] = {0,0,0,0,0,0,0,0};
#pragma unroll
    for (int b = 0; b < 8; ++b) {
      const float cf = par[c*8 + b];
      const float* row = bas + (((b*ospan + oo)*8 + i) << 3);
#pragma unroll
      for (int j = 0; j < 8; ++j) acc[j] += cf * row[j];
    }
    float* dst;
    if (m == 1)      dst = sW + 576 + ((c*8 + i) << 3);
    else if (m == 0) dst = sW + (c*8 + i)*9;
    else             dst = sW + 1088 + (m - 2)*576 + (c*8 + i)*9;
#pragma unroll
    for (int j = 0; j < 8; ++j) dst[j] = acc[j];
  }
  __syncthreads();

  const int mode = sFlagB ? 1 : (sFlagF ? 2 : 0);

  const int v = (blockIdx.x << 2) + wv;   // grid is exactly NVERT/4
  const int n = lane >> 1;                // neighbor 0..31
  const int h = lane & 1;                 // channel half
  const int cbase = h << 2;
  float* sFw = sF[wv];

  // ---- stage ptm[v] (8KB) coalesced into padded LDS rows ----
  {
    const float4* p4 = (const float4*)(ptm + (size_t)v * 2048);
#pragma unroll
    for (int t = 0; t < 8; ++t) {
      const int g = lane + (t << 6);
      const float4 val = p4[g];
      const int row = g >> 4;
      const int rr  = g & 15;
      *(float4*)&sFw[row*68 + (rr << 2)] = val;
    }
  }

  // ---- gather neighbor features into regs ----
  const int nbv = nbr[(v << 5) + n];
  const float* xb = x + ((size_t)nbv << 6) + (cbase << 3);
  float xn[4][8];
#pragma unroll
  for (int c4 = 0; c4 < 4; ++c4) {
    const float4 a = *(const float4*)(xb + (c4 << 3));
    const float4 b = *(const float4*)(xb + (c4 << 3) + 4);
    xn[c4][0]=a.x; xn[c4][1]=a.y; xn[c4][2]=a.z; xn[c4][3]=a.w;
    xn[c4][4]=b.x; xn[c4][5]=b.y; xn[c4][6]=b.z; xn[c4][7]=b.w;
  }

  __syncthreads();  // staging visible

  // ---- transport: f[c,i] = ptm_row_i . xn[c] ----
  float f[4][8];
#pragma unroll
  for (int i = 0; i < 8; ++i) {
    const float4 pa = *(const float4*)&sFw[n*68 + (i << 3)];
    const float4 pb = *(const float4*)&sFw[n*68 + (i << 3) + 4];
#pragma unroll
    for (int c4 = 0; c4 < 4; ++c4) {
      f[c4][i] = pa.x*xn[c4][0] + pa.y*xn[c4][1] + pa.z*xn[c4][2] + pa.w*xn[c4][3]
               + pb.x*xn[c4][4] + pb.y*xn[c4][5] + pb.z*xn[c4][6] + pb.w*xn[c4][7];
    }
  }

  // ---- K partial (this lane's 4 channels) ----
  float Kp[8] = {0,0,0,0,0,0,0,0};
#pragma unroll
  for (int c4 = 0; c4 < 4; ++c4) {
    const float* wk = sW + 576 + ((cbase + c4) << 6);
#pragma unroll
    for (int i = 0; i < 8; ++i) {
      const float4 wa = *(const float4*)(wk + (i << 3));
      const float4 wb = *(const float4*)(wk + (i << 3) + 4);
      Kp[i] += wa.x*f[c4][0] + wa.y*f[c4][1] + wa.z*f[c4][2] + wa.w*f[c4][3]
             + wb.x*f[c4][4] + wb.y*f[c4][5] + wb.z*f[c4][6] + wb.w*f[c4][7];
    }
  }

  // ---- write f over the ptm region (pair-owned rows; same-wave DS is in-order) ----
#pragma unroll
  for (int c4 = 0; c4 < 4; ++c4) {
    *(float4*)&sFw[n*68 + ((cbase + c4) << 3)]     = make_float4(f[c4][0], f[c4][1], f[c4][2], f[c4][3]);
    *(float4*)&sFw[n*68 + ((cbase + c4) << 3) + 4] = make_float4(f[c4][4], f[c4][5], f[c4][6], f[c4][7]);
  }

  // ---- Q (lane=(c,i) mapping) ----
  {
    const int qc_ = lane >> 3;
    const int qi  = lane & 7;
    const float* xvr = x + ((size_t)v << 6) + (qc_ << 3);
    const float4 xa  = *(const float4*)xvr;
    const float4 xb2 = *(const float4*)(xvr + 4);
    const float* wq = sW + (qc_*8 + qi)*9;
    float qa = wq[0]*xa.x + wq[1]*xa.y + wq[2]*xa.z + wq[3]*xa.w
             + wq[4]*xb2.x + wq[5]*xb2.y + wq[6]*xb2.z + wq[7]*xb2.w;
    qa += __shfl_xor(qa, 8);
    qa += __shfl_xor(qa, 16);
    qa += __shfl_xor(qa, 32);
    if (lane < 8) sQ[wv][lane] = qa;
  }
  __syncthreads();

  // ---- score, mask, attention, Taylor coefs ----
#pragma unroll
  for (int i = 0; i < 8; ++i) Kp[i] += __shfl_xor(Kp[i], 1);
  float s = 0.0f;
#pragma unroll
  for (int i = 0; i < 8; ++i) s += fmaxf(sQ[wv][i] + Kp[i], 0.0f);
  s *= 0.125f;
  const int mi = (v << 5) + n;
  bool mk;
  if (mode == 1)      mk = ((const unsigned char*)maskp)[mi] != 0;
  else if (mode == 2) mk = ((((const unsigned int*)maskp)[mi]) & 0x7FFFFFFFu) != 0u;
  else                mk = ((const int*)maskp)[mi] != 0;
  if (!mk) s = 0.0f;
  float d = s;
  d += __shfl_xor(d, 2);
  d += __shfl_xor(d, 4);
  d += __shfl_xor(d, 8);
  d += __shfl_xor(d, 16);
  d += __shfl_xor(d, 32);
  const float att = s / fmaxf(d, 1e-8f);
  const float2 uu = *(const float2*)(rpu + ((size_t)mi << 1));
  if (h == 0) {
    float* wd = &sAtt[wv][n << 3];
    *(float4*)wd       = make_float4(att, att*uu.x, att*uu.y, att*uu.x*uu.x);
    *(float2*)(wd + 4) = make_float2(2.0f*att*uu.x*uu.y, att*uu.y*uu.y);
  }
  __syncthreads();

  // ---- h_o[c,j] = sum_n coef_o(n) * f[n,c,j]   (lane = c*8+j) ----
  float hacc[6] = {0,0,0,0,0,0};
#pragma unroll 8
  for (int k = 0; k < 32; ++k) {
    const float fv = sFw[k*68 + lane];
    const float4 wA = *(const float4*)&sAtt[wv][k << 3];
    const float2 wB = *(const float2*)&sAtt[wv][(k << 3) + 4];
    hacc[0] += wA.x*fv; hacc[1] += wA.y*fv; hacc[2] += wA.z*fv;
    hacc[3] += wA.w*fv; hacc[4] += wB.x*fv; hacc[5] += wB.y*fv;
  }

  // ---- out[c,i] = sum_o sum_j WV_o[c,i,j] h_o[c,j]  (partial over j, pair/quad reduce) ----
  const int fc = lane >> 3;
  const int fj = lane & 7;
  float myout = 0.0f;
#pragma unroll
  for (int i = 0; i < 8; ++i) {
    const float* wvp = sW + 1088 + (fc*8 + i)*9 + fj;
    float p = wvp[0]*hacc[0] + wvp[576]*hacc[1] + wvp[1152]*hacc[2]
            + wvp[1728]*hacc[3] + wvp[2304]*hacc[4] + wvp[2880]*hacc[5];
    p += __shfl_xor(p, 1);
    p += __shfl_xor(p, 2);
    p += __shfl_xor(p, 4);
    if (fj == i) myout = p;
  }
  out[((size_t)v << 6) + lane] = myout;
}

extern "C" void kernel_launch(void* const* d_in, const int* in_sizes, int n_in,
                              void* d_out, int out_size, void* d_ws, size_t ws_size,
                              hipStream_t stream) {
  const float* x   = (const float*)d_in[0];
  const int*   nb  = (const int*)d_in[1];
  const void*  msk = d_in[2];
  const float* ptm = (const float*)d_in[3];
  const float* rpu = (const float*)d_in[4];
  const float* rb  = (const float*)d_in[5];
  const float* qc  = (const float*)d_in[6];
  const float* kc  = (const float*)d_in[7];
  const float* vb0 = (const float*)d_in[8];
  const float* vb1 = (const float*)d_in[9];
  const float* vb2 = (const float*)d_in[10];
  const float* vp0 = (const float*)d_in[11];
  const float* vp1 = (const float*)d_in[12];
  const float* vp2 = (const float*)d_in[13];
  (void)in_sizes; (void)n_in; (void)out_size; (void)d_ws; (void)ws_size;

  ge_attn<<<NVERT / 4, 256, 0, stream>>>(x, nb, msk, ptm, rpu, rb, qc, kc,
                                         vb0, vb1, vb2, vp0, vp1, vp2,
                                         (float*)d_out);
}